// Round 1
// baseline (312.810 us; speedup 1.0000x reference)
//
#include <hip/hip_runtime.h>

// GlobalQuantizedLatent: per-element nearest-codebook quantization.
// N = 16,777,216 f32, V = 16 codebook entries (linspace(-0.5, 0.5, 16)).
// Outputs (concatenated flat, all read back as f32 by the harness):
//   [0,   N) : x            (copy of input)
//   [N,  2N) : quantized    (values[argmin |x - values|])
//   [2N, 3N) : z_hat        (== quantized numerically in forward)
//   [3N, 4N) : indices      (argmin index, stored as float)
//
// Memory-bound: 64 MiB read + 256 MiB write => ~53 us floor at 6.3 TB/s.
// Each thread processes 4 elements via float4 loads/stores (16 B/lane).

#define BLOCK 256
#define NVALS 16

__global__ __launch_bounds__(BLOCK) void
GlobalQuantizedLatent_87900800680047_kernel(const float* __restrict__ x,
                                            const float* __restrict__ values,
                                            float* __restrict__ out,
                                            int n) {
    const int i4 = (blockIdx.x * BLOCK + threadIdx.x) * 4;
    if (i4 >= n) return;

    // Codebook: wave-uniform pointer + constant offsets -> scalar loads.
    float v[NVALS];
#pragma unroll
    for (int j = 0; j < NVALS; ++j) v[j] = values[j];

    const float4 xv = *reinterpret_cast<const float4*>(x + i4);
    const float xs[4] = {xv.x, xv.y, xv.z, xv.w};

    float q[4];
    float idxf[4];
#pragma unroll
    for (int e = 0; e < 4; ++e) {
        // Exact replication of jnp.argmin(|x - values|): first minimum wins
        // (strict <), matching the reference tie-break bit-for-bit.
        float best = fabsf(xs[e] - v[0]);
        int bi = 0;
#pragma unroll
        for (int j = 1; j < NVALS; ++j) {
            const float d = fabsf(xs[e] - v[j]);
            if (d < best) { best = d; bi = j; }
        }
        q[e] = v[bi];
        idxf[e] = (float)bi;
    }

    const size_t nn = (size_t)n;
    float* o_x   = out;
    float* o_q   = out + nn;
    float* o_zh  = out + 2 * nn;
    float* o_idx = out + 3 * nn;

    const float4 qv = make_float4(q[0], q[1], q[2], q[3]);
    const float4 iv = make_float4(idxf[0], idxf[1], idxf[2], idxf[3]);

    *reinterpret_cast<float4*>(o_x + i4)   = xv;
    *reinterpret_cast<float4*>(o_q + i4)   = qv;
    *reinterpret_cast<float4*>(o_zh + i4)  = qv;
    *reinterpret_cast<float4*>(o_idx + i4) = iv;
}

extern "C" void kernel_launch(void* const* d_in, const int* in_sizes, int n_in,
                              void* d_out, int out_size, void* d_ws, size_t ws_size,
                              hipStream_t stream) {
    const float* x      = (const float*)d_in[0];
    const float* values = (const float*)d_in[1];
    float* out          = (float*)d_out;
    const int n = in_sizes[0];  // 16,777,216

    const int elems_per_block = BLOCK * 4;
    const int grid = (n + elems_per_block - 1) / elems_per_block;  // 16384

    GlobalQuantizedLatent_87900800680047_kernel<<<grid, BLOCK, 0, stream>>>(
        x, values, out, n);
}